// Round 14
// baseline (446.747 us; speedup 1.0000x reference)
//
#include <hip/hip_runtime.h>

#define N_NODES 10000
#define FEATS 32
#define HEADS 4
#define SAMPLES 256
#define N_BATCH 2048
#define NGROUP 40                       // ceil(N_NODES / 256)
#define NWORDS (NGROUP * 4)             // 160 u64 words per mask row

typedef float f32x4 __attribute__((ext_vector_type(4)));
typedef unsigned long long u64;

// ws layout: u64 mask_table[N_NODES][NWORDS] = 12.8 MB (indexed by node id).
#define WS_NEEDED (N_NODES * NWORDS * 8)

// ======= Kernel 1 (R11 proven): per-NODE mask dedup ========================
// Block i in [0,4096): endpoint v = edge_flat[i]. First occurrence streams
// edge_mat row v (40 KB sequential, MLP-10 batched) -> sign bitmask in
// mask_table[v]; duplicates exit after an L2-resident scan of edge[0..i).
// Blocks < N_BATCH also zero out[] for k2's atomic accumulate.
__global__ __launch_bounds__(256) void mask_dedup_kernel(
    const int* __restrict__ edge,        // flat (N_BATCH*2)
    const float* __restrict__ edge_mat,
    u64* __restrict__ mask_table,
    float* __restrict__ out)
{
    const int bid  = blockIdx.x;
    const int tid  = threadIdx.x;
    const int w    = tid >> 6;
    const int lane = tid & 63;

    if (tid == 0 && bid < N_BATCH) out[bid] = 0.f;

    const int v = edge[bid];

    __shared__ int s_dup;
    if (tid == 0) s_dup = 0;
    __syncthreads();
    for (int j = tid; j < bid; j += 256)
        if (edge[j] == v) s_dup = 1;
    __syncthreads();
    if (s_dup) return;

    const float* rp = edge_mat + (size_t)v * N_NODES;
    u64* wsn = mask_table + (size_t)v * NWORDS;

    // Batch phase: all 10 x 1 KB loads in flight before any ballot.
    f32x4 val[10];
    #pragma unroll
    for (int i = 0; i < 10; ++i) {
        const int base = (i * 4 + w) * 256 + lane * 4;
        f32x4 t = {-1.f, -1.f, -1.f, -1.f};
        if (base < N_NODES) t = *(const f32x4*)(rp + base);
        val[i] = t;
    }
    #pragma unroll
    for (int i = 0; i < 10; ++i) {
        const int g = i * 4 + w;
        u64 b0 = __ballot(val[i].x > 0.f);
        u64 b1 = __ballot(val[i].y > 0.f);
        u64 b2 = __ballot(val[i].z > 0.f);
        u64 b3 = __ballot(val[i].w > 0.f);
        if (lane < 4) {
            u64 bb = lane == 0 ? b0 : lane == 1 ? b1 : lane == 2 ? b2 : b3;
            wsn[g * 4 + lane] = bb;
        }
    }
}

// ======= Kernel 2 (R12 single variable): wave = (edge, head, SIDE) =========
// Grid 4096 x 256. Block b: head h = b & 3 (b % 8 round-robin -> XCD x only
// touches pos[x & 3], 1.28 MB L2-resident); base = b >> 2 in [0,1024).
// Wave w: edge n = base + (w & 1) * 1024, side = w >> 1. Halved per-wave
// state (one side: 16 VGPR anchors, mm[4], one 1.25 KB mask row) + MLP-4
// batching targets <=64 VGPR under __launch_bounds__(256, 8) -> 8 waves/SIMD
// (2x R11's occupancy) to hide gather latency. 4 lanes/row, 2-level shfl_xor
// butterfly; em/exp/acc redundant per lane (4x, folded via +32). Sides
// recombine in LDS; one division per (edge, head); 4 atomics per edge.
__global__ __launch_bounds__(256, 8) void madgraph_k2(
    const int* __restrict__ edge,
    const int* __restrict__ mid0,
    const int* __restrict__ mid1,
    const float* __restrict__ pos,
    const float* __restrict__ field,
    const float* __restrict__ unc,
    const u64* __restrict__ mask_table,
    float* __restrict__ out)
{
    const int b    = blockIdx.x;
    const int h    = b & 3;
    const int base = b >> 2;              // [0, 1024)
    const int tid  = threadIdx.x;
    const int w    = tid >> 6;
    const int lane = tid & 63;
    const int n    = base + (w & 1) * 1024;
    const int side = w >> 1;

    __shared__ u64 s_mask[4][NWORDS];     // one row per wave, 5 KB total
    __shared__ float s_nd[2][2][2];       // [edge slot][side][num|den]

    const int src = edge[2 * n];
    const int dst = edge[2 * n + 1];
    const float U = unc[0];

    // side0 uses row dst (symmetry: edge_mat[m,dst]==edge_mat[dst,m]);
    // side1 uses row src.
    const u64* wr = mask_table + (size_t)(side ? src : dst) * NWORDS;
    #pragma unroll
    for (int k = 0; k < 3; ++k) {
        const int idx = k * 64 + lane;
        if (idx < NWORDS) s_mask[w][idx] = wr[idx];
    }

    const float* posh   = pos   + (size_t)h * N_NODES * FEATS;
    const float* fieldh = field + (size_t)h * N_NODES * FEATS;

    const int q = lane & 3;    // lane's chunk pair: q and q+4
    const int g = lane >> 2;   // row-group index within 16

    // This side's anchor/field slices (4 float4 = 16 VGPRs).
    float4 A0, A1, F0, F1;
    {
        const float4* pa = (const float4*)(posh   + (size_t)(side ? dst : src) * FEATS);
        const float4* pf = (const float4*)(fieldh + (size_t)(side ? src : dst) * FEATS);
        A0 = pa[q]; A1 = pa[q + 4];
        F0 = pf[q]; F1 = pf[q + 4];
    }

    const size_t sb = ((size_t)h * N_BATCH + n) * SAMPLES;
    const int* mids = side ? mid1 : mid0;
    int mm[4];
    #pragma unroll
    for (int c = 0; c < 4; ++c)
        mm[c] = mids[sb + c * 64 + lane];

    float num = 0.f, den = 0.f;

    #pragma unroll
    for (int c = 0; c < 4; ++c) {
        int mA[4];
        #pragma unroll
        for (int t = 0; t < 4; ++t)
            mA[t] = __shfl(mm[c], t * 16 + g);

        #pragma unroll
        for (int half = 0; half < 2; ++half) {
            // MLP-4 batch: two rows' both halves issued before consumption.
            const int ta = 2 * half, tb = 2 * half + 1;
            const float4* ra = (const float4*)(posh + (size_t)mA[ta] * FEATS);
            const float4* rb = (const float4*)(posh + (size_t)mA[tb] * FEATS);
            float4 Ba0 = ra[q], Ba1 = ra[q + 4];
            float4 Bb0 = rb[q], Bb1 = rb[q + 4];

            #pragma unroll
            for (int u = 0; u < 2; ++u) {
                const int m  = u ? mA[tb] : mA[ta];
                const float4 B0 = u ? Bb0 : Ba0;
                const float4 B1 = u ? Bb1 : Ba1;

                float dh = 0.f, nh = 0.f;
                {
                    float dx = A0.x - B0.x, dy = A0.y - B0.y,
                          dz = A0.z - B0.z, dw = A0.w - B0.w;
                    dh += dx * F0.x + dy * F0.y + dz * F0.z + dw * F0.w;
                    nh += dx * dx + dy * dy + dz * dz + dw * dw;
                }
                {
                    float dx = A1.x - B1.x, dy = A1.y - B1.y,
                          dz = A1.z - B1.z, dw = A1.w - B1.w;
                    dh += dx * F1.x + dy * F1.y + dz * F1.z + dw * F1.w;
                    nh += dx * dx + dy * dy + dz * dz + dw * dw;
                }
                dh += __shfl_xor(dh, 1); nh += __shfl_xor(nh, 1);
                dh += __shfl_xor(dh, 2); nh += __shfl_xor(nh, 2);

                const u64 wbits = s_mask[w][((m >> 8) << 2) + (m & 3)];
                const float em = ((wbits >> ((m >> 2) & 63)) & 1ull) ? U : -U;

                const float wgt = __expf(1.0f - sqrtf(nh));
                num += (dh + em) * wgt;   // each sample counted by 4 lanes
                den += wgt;
            }
        }
    }

    // Wave-wide butterfly reduction (64 lanes).
    #pragma unroll
    for (int off = 32; off > 0; off >>= 1) {
        num += __shfl_xor(num, off);
        den += __shfl_xor(den, off);
    }
    if (lane == 0) {
        s_nd[w & 1][side][0] = num;
        s_nd[w & 1][side][1] = den;
    }
    __syncthreads();

    if (tid < 2) {
        const int ne   = base + tid * 1024;
        const float n4 = s_nd[tid][0][0] + s_nd[tid][1][0];
        const float d4 = s_nd[tid][0][1] + s_nd[tid][1][1];
        // 4x-counted; sentinels add 8 true -> +32 scaled:
        // 0.25*(4N)/(4D+32) == 0.25*N/(D+8). k1 zeroed out[] this launch.
        atomicAdd(out + ne, 0.25f * (n4 / (d4 + 32.0f)));
    }
}

// ======= Fallback (R8 exact): per-edge masks, no dedup =====================
__global__ __launch_bounds__(256) void mask_kernel(
    const int* __restrict__ edge,
    const float* __restrict__ edge_mat,
    u64* __restrict__ ws_mask,
    float* __restrict__ out)
{
    const int n    = blockIdx.x;
    const int tid  = threadIdx.x;
    const int wave = tid >> 6;
    const int lane = tid & 63;
    const int src = edge[2 * n];
    const int dst = edge[2 * n + 1];
    if (tid == 0) out[n] = 0.f;
    u64* wsn = ws_mask + (size_t)n * 2 * NWORDS;
    #pragma unroll
    for (int r = 0; r < 2; ++r) {
        const float* rp = edge_mat + (size_t)(r ? src : dst) * N_NODES;
        for (int g = wave; g < NGROUP; g += 4) {
            int base = g * 256 + lane * 4;
            float4 v = make_float4(-1.f, -1.f, -1.f, -1.f);
            if (base < N_NODES) v = *(const float4*)(rp + base);
            u64 b0 = __ballot(v.x > 0.f);
            u64 b1 = __ballot(v.y > 0.f);
            u64 b2 = __ballot(v.z > 0.f);
            u64 b3 = __ballot(v.w > 0.f);
            if (lane < 4) {
                u64 bb = lane == 0 ? b0 : lane == 1 ? b1 : lane == 2 ? b2 : b3;
                wsn[r * NWORDS + g * 4 + lane] = bb;
            }
        }
    }
}

__global__ __launch_bounds__(256, 4) void madgraph_kernel_fb(
    const int* __restrict__ edge,
    const int* __restrict__ mid0,
    const int* __restrict__ mid1,
    const float* __restrict__ pos,
    const float* __restrict__ field,
    const float* __restrict__ unc,
    const u64* __restrict__ ws_mask,
    float* __restrict__ out)
{
    const int b    = blockIdx.x;
    const int h    = b & 3;
    const int tid  = threadIdx.x;
    const int w    = tid >> 6;
    const int lane = tid & 63;
    const int n    = (b >> 2) + 512 * w;

    __shared__ u64 s_mask[4][2 * NWORDS];

    const int src = edge[2 * n];
    const int dst = edge[2 * n + 1];
    const float U = unc[0];

    const u64* wsn = ws_mask + (size_t)n * 2 * NWORDS;
    #pragma unroll
    for (int k = 0; k < 5; ++k)
        s_mask[w][k * 64 + lane] = wsn[k * 64 + lane];

    const float* posh   = pos   + (size_t)h * N_NODES * FEATS;
    const float* fieldh = field + (size_t)h * N_NODES * FEATS;
    const int q = lane & 3;
    const int g = lane >> 2;

    float4 A[2][2], F[2][2];
    #pragma unroll
    for (int sd = 0; sd < 2; ++sd) {
        const float4* pa = (const float4*)(posh   + (size_t)(sd ? dst : src) * FEATS);
        const float4* pf = (const float4*)(fieldh + (size_t)(sd ? src : dst) * FEATS);
        A[sd][0] = pa[q]; A[sd][1] = pa[q + 4];
        F[sd][0] = pf[q]; F[sd][1] = pf[q + 4];
    }

    const size_t sb = ((size_t)h * N_BATCH + n) * SAMPLES;
    int mm[8];
    #pragma unroll
    for (int c = 0; c < 8; ++c)
        mm[c] = (c < 4 ? mid0 : mid1)[sb + (c & 3) * 64 + lane];

    float num = 0.f, den = 0.f;
    #pragma unroll
    for (int c = 0; c < 8; ++c) {
        const int side = c >> 2;
        int    mArr[4];
        float4 B0[4], B1[4];
        #pragma unroll
        for (int t = 0; t < 4; ++t)
            mArr[t] = __shfl(mm[c], t * 16 + g);
        #pragma unroll
        for (int t = 0; t < 4; ++t) {
            const float4* rp = (const float4*)(posh + (size_t)mArr[t] * FEATS);
            B0[t] = rp[q];
            B1[t] = rp[q + 4];
        }
        #pragma unroll
        for (int t = 0; t < 4; ++t) {
            float dh = 0.f, nh = 0.f;
            {
                float4 a = A[side][0], f = F[side][0];
                float dx = a.x - B0[t].x, dy = a.y - B0[t].y,
                      dz = a.z - B0[t].z, dw = a.w - B0[t].w;
                dh += dx * f.x + dy * f.y + dz * f.z + dw * f.w;
                nh += dx * dx + dy * dy + dz * dz + dw * dw;
            }
            {
                float4 a = A[side][1], f = F[side][1];
                float dx = a.x - B1[t].x, dy = a.y - B1[t].y,
                      dz = a.z - B1[t].z, dw = a.w - B1[t].w;
                dh += dx * f.x + dy * f.y + dz * f.z + dw * f.w;
                nh += dx * dx + dy * dy + dz * dz + dw * dw;
            }
            dh += __shfl_xor(dh, 1); nh += __shfl_xor(nh, 1);
            dh += __shfl_xor(dh, 2); nh += __shfl_xor(nh, 2);
            const u64 wbits =
                s_mask[w][side * NWORDS + ((mArr[t] >> 8) << 2) + (mArr[t] & 3)];
            const float em = ((wbits >> ((mArr[t] >> 2) & 63)) & 1ull) ? U : -U;
            const float wgt = __expf(1.0f - sqrtf(nh));
            num += (dh + em) * wgt;
            den += wgt;
        }
    }
    #pragma unroll
    for (int off = 32; off > 0; off >>= 1) {
        num += __shfl_xor(num, off);
        den += __shfl_xor(den, off);
    }
    if (lane == 0)
        atomicAdd(out + n, 0.25f * (num / (den + 32.0f)));
}

extern "C" void kernel_launch(void* const* d_in, const int* in_sizes, int n_in,
                              void* d_out, int out_size, void* d_ws, size_t ws_size,
                              hipStream_t stream) {
    const int*   edge     = (const int*)  d_in[0];
    const int*   mid0     = (const int*)  d_in[1];
    const int*   mid1     = (const int*)  d_in[2];
    const float* pos      = (const float*)d_in[3];
    const float* field    = (const float*)d_in[4];
    const float* unc      = (const float*)d_in[5];
    const float* edge_mat = (const float*)d_in[6];
    float*       out      = (float*)d_out;

    if (ws_size >= (size_t)WS_NEEDED) {
        u64* mask_table = (u64*)d_ws;   // 12.8 MB, indexed by node id
        mask_dedup_kernel<<<2 * N_BATCH, 256, 0, stream>>>(edge, edge_mat,
                                                           mask_table, out);
        madgraph_k2<<<2 * N_BATCH, 256, 0, stream>>>(edge, mid0, mid1, pos,
                                                     field, unc, mask_table, out);
    } else {
        u64* ws_mask = (u64*)d_ws;      // 5.24 MB per-edge masks
        mask_kernel<<<N_BATCH, 256, 0, stream>>>(edge, edge_mat, ws_mask, out);
        madgraph_kernel_fb<<<N_BATCH, 256, 0, stream>>>(edge, mid0, mid1, pos,
                                                        field, unc, ws_mask, out);
    }
}

// Round 15
// 58.616 us; speedup vs baseline: 7.6216x; 7.6216x over previous
//
#include <hip/hip_runtime.h>

#define N_NODES 10000
#define FEATS 32
#define HEADS 4
#define SAMPLES 256
#define N_BATCH 2048
#define NGROUP 40                       // ceil(N_NODES / 256)
#define NWORDS (NGROUP * 4)             // 160 u64 words per mask row

typedef float f32x4 __attribute__((ext_vector_type(4)));
typedef unsigned long long u64;

// ws layout (dedup path): u64 mask_table[N_NODES][NWORDS] = 12.8 MB.
#define WS_NEEDED (N_NODES * NWORDS * 8)

// ======= Kernel 1 (dedup): per-NODE sign bitmasks of edge_mat rows =========
// Block i in [0,4096): endpoint v = edge_flat[i]. If v occurred at any j<i,
// exit (first occurrence builds the row; pure function of edge[] ->
// deterministic). Else stream row v (40 KB sequential, MLP depth 10 per
// wave) and ballot sign bits into mask_table[v]. ~3360 unique endpoints
// -> ~134 MB HBM instead of 164 MB. Blocks < N_BATCH also zero out[].
__global__ __launch_bounds__(256) void mask_dedup_kernel(
    const int* __restrict__ edge,        // flat (N_BATCH*2)
    const float* __restrict__ edge_mat,
    u64* __restrict__ mask_table,
    float* __restrict__ out)
{
    const int bid  = blockIdx.x;
    const int tid  = threadIdx.x;
    const int w    = tid >> 6;
    const int lane = tid & 63;

    if (tid == 0 && bid < N_BATCH) out[bid] = 0.f;

    const int v = edge[bid];

    // Duplicate scan over earlier endpoints (16 KB, L2-resident).
    __shared__ int s_dup;
    if (tid == 0) s_dup = 0;
    __syncthreads();
    for (int j = tid; j < bid; j += 256)
        if (edge[j] == v) s_dup = 1;
    __syncthreads();
    if (s_dup) return;

    const float* rp = edge_mat + (size_t)v * N_NODES;
    u64* wsn = mask_table + (size_t)v * NWORDS;

    // Batch phase: all 10 x 1 KB loads in flight before any ballot.
    f32x4 val[10];
    #pragma unroll
    for (int i = 0; i < 10; ++i) {
        const int base = (i * 4 + w) * 256 + lane * 4;
        f32x4 t = {-1.f, -1.f, -1.f, -1.f};
        if (base < N_NODES) t = *(const f32x4*)(rp + base);
        val[i] = t;
    }
    // Ballot phase.
    #pragma unroll
    for (int i = 0; i < 10; ++i) {
        const int g = i * 4 + w;
        u64 b0 = __ballot(val[i].x > 0.f);
        u64 b1 = __ballot(val[i].y > 0.f);
        u64 b2 = __ballot(val[i].z > 0.f);
        u64 b3 = __ballot(val[i].w > 0.f);
        if (lane < 4) {
            u64 bb = lane == 0 ? b0 : lane == 1 ? b1 : lane == 2 ? b2 : b3;
            wsn[g * 4 + lane] = bb;
        }
    }
}

// ======= Kernel 2: register-direct gather (R8/R11 proven shape) ============
// Block b: head h = b & 3; wave w handles edge n = (b>>2) + 512w. Round-robin
// XCD (b % 8) => XCD x only touches pos[x & 3] (1.28 MB, L2-resident).
// Per chunk: ALL 8 gathers (4 rows x 2 halves, 16 rows x 64 B contiguous per
// instr) batched into registers before consumption (MLP depth 8), then 4
// compute iters. 4-lane/row split, 2-level shfl_xor butterfly; em/exp/acc
// redundant per lane (4x counted, folded via den+32). Masks read per NODE.
// NOTE (R13 lesson): do NOT raise the launch_bounds waves/EU arg — this
// kernel needs ~128 VGPR; forcing 8 waves/EU (64 VGPR) spills to scratch,
// which floods L2/HBM (562 MB fetch, 7x slowdown, measured).
__global__ __launch_bounds__(256, 4) void madgraph_kernel(
    const int* __restrict__ edge,
    const int* __restrict__ mid0,
    const int* __restrict__ mid1,
    const float* __restrict__ pos,
    const float* __restrict__ field,
    const float* __restrict__ unc,
    const u64* __restrict__ mask_table,
    float* __restrict__ out)
{
    const int b    = blockIdx.x;
    const int h    = b & 3;
    const int tid  = threadIdx.x;
    const int w    = tid >> 6;
    const int lane = tid & 63;
    const int n    = (b >> 2) + 512 * w;

    __shared__ u64 s_mask[4][2 * NWORDS];   // [w][0..159]=dst row, [160..)=src

    const int src = edge[2 * n];
    const int dst = edge[2 * n + 1];
    const float U = unc[0];

    const u64* wdst = mask_table + (size_t)dst * NWORDS;  // side0 (symmetry)
    const u64* wsrc = mask_table + (size_t)src * NWORDS;  // side1
    #pragma unroll
    for (int k = 0; k < 5; ++k) {
        const int idx = k * 64 + lane;
        s_mask[w][idx] = (idx < NWORDS) ? wdst[idx] : wsrc[idx - NWORDS];
    }

    const float* posh   = pos   + (size_t)h * N_NODES * FEATS;
    const float* fieldh = field + (size_t)h * N_NODES * FEATS;
    const int q = lane & 3;    // lane's chunk pair: q and q+4
    const int g = lane >> 2;   // row-group index within 16

    float4 A[2][2], F[2][2];
    #pragma unroll
    for (int sd = 0; sd < 2; ++sd) {
        const float4* pa = (const float4*)(posh   + (size_t)(sd ? dst : src) * FEATS);
        const float4* pf = (const float4*)(fieldh + (size_t)(sd ? src : dst) * FEATS);
        A[sd][0] = pa[q]; A[sd][1] = pa[q + 4];
        F[sd][0] = pf[q]; F[sd][1] = pf[q + 4];
    }

    const size_t sb = ((size_t)h * N_BATCH + n) * SAMPLES;
    int mm[8];
    #pragma unroll
    for (int c = 0; c < 8; ++c)
        mm[c] = (c < 4 ? mid0 : mid1)[sb + (c & 3) * 64 + lane];

    float num = 0.f, den = 0.f;
    #pragma unroll
    for (int c = 0; c < 8; ++c) {
        const int side = c >> 2;

        // Batch phase: issue all 8 independent gathers for this chunk.
        int    mArr[4];
        float4 B0[4], B1[4];
        #pragma unroll
        for (int t = 0; t < 4; ++t)
            mArr[t] = __shfl(mm[c], t * 16 + g);
        #pragma unroll
        for (int t = 0; t < 4; ++t) {
            const float4* rp = (const float4*)(posh + (size_t)mArr[t] * FEATS);
            B0[t] = rp[q];
            B1[t] = rp[q + 4];
        }

        // Compute phase.
        #pragma unroll
        for (int t = 0; t < 4; ++t) {
            float dh = 0.f, nh = 0.f;
            {
                float4 a = A[side][0], f = F[side][0];
                float dx = a.x - B0[t].x, dy = a.y - B0[t].y,
                      dz = a.z - B0[t].z, dw = a.w - B0[t].w;
                dh += dx * f.x + dy * f.y + dz * f.z + dw * f.w;
                nh += dx * dx + dy * dy + dz * dz + dw * dw;
            }
            {
                float4 a = A[side][1], f = F[side][1];
                float dx = a.x - B1[t].x, dy = a.y - B1[t].y,
                      dz = a.z - B1[t].z, dw = a.w - B1[t].w;
                dh += dx * f.x + dy * f.y + dz * f.z + dw * f.w;
                nh += dx * dx + dy * dy + dz * dz + dw * dw;
            }
            dh += __shfl_xor(dh, 1); nh += __shfl_xor(nh, 1);
            dh += __shfl_xor(dh, 2); nh += __shfl_xor(nh, 2);

            const u64 wbits =
                s_mask[w][side * NWORDS + ((mArr[t] >> 8) << 2) + (mArr[t] & 3)];
            const float em = ((wbits >> ((mArr[t] >> 2) & 63)) & 1ull) ? U : -U;

            const float wgt = __expf(1.0f - sqrtf(nh));
            num += (dh + em) * wgt;   // each sample counted by 4 lanes
            den += wgt;
        }
    }

    #pragma unroll
    for (int off = 32; off > 0; off >>= 1) {
        num += __shfl_xor(num, off);
        den += __shfl_xor(den, off);
    }
    if (lane == 0) {
        // 4x-counted; sentinels add 8 true -> +32 scaled:
        // 0.25*(4N)/(4D+32) == 0.25*N/(D+8). k1 zeroed out[n] this launch.
        atomicAdd(out + n, 0.25f * (num / (den + 32.0f)));
    }
}

// ======= Fallback (per-edge masks, no dedup) ===============================
__global__ __launch_bounds__(256) void mask_kernel(
    const int* __restrict__ edge,
    const float* __restrict__ edge_mat,
    u64* __restrict__ ws_mask,
    float* __restrict__ out)
{
    const int n    = blockIdx.x;
    const int tid  = threadIdx.x;
    const int wave = tid >> 6;
    const int lane = tid & 63;
    const int src = edge[2 * n];
    const int dst = edge[2 * n + 1];
    if (tid == 0) out[n] = 0.f;
    u64* wsn = ws_mask + (size_t)n * 2 * NWORDS;
    #pragma unroll
    for (int r = 0; r < 2; ++r) {
        const float* rp = edge_mat + (size_t)(r ? src : dst) * N_NODES;
        for (int g = wave; g < NGROUP; g += 4) {
            int base = g * 256 + lane * 4;
            float4 v = make_float4(-1.f, -1.f, -1.f, -1.f);
            if (base < N_NODES) v = *(const float4*)(rp + base);
            u64 b0 = __ballot(v.x > 0.f);
            u64 b1 = __ballot(v.y > 0.f);
            u64 b2 = __ballot(v.z > 0.f);
            u64 b3 = __ballot(v.w > 0.f);
            if (lane < 4) {
                u64 bb = lane == 0 ? b0 : lane == 1 ? b1 : lane == 2 ? b2 : b3;
                wsn[r * NWORDS + g * 4 + lane] = bb;
            }
        }
    }
}

__global__ __launch_bounds__(256, 4) void madgraph_kernel_fb(
    const int* __restrict__ edge,
    const int* __restrict__ mid0,
    const int* __restrict__ mid1,
    const float* __restrict__ pos,
    const float* __restrict__ field,
    const float* __restrict__ unc,
    const u64* __restrict__ ws_mask,
    float* __restrict__ out)
{
    const int b    = blockIdx.x;
    const int h    = b & 3;
    const int tid  = threadIdx.x;
    const int w    = tid >> 6;
    const int lane = tid & 63;
    const int n    = (b >> 2) + 512 * w;

    __shared__ u64 s_mask[4][2 * NWORDS];

    const int src = edge[2 * n];
    const int dst = edge[2 * n + 1];
    const float U = unc[0];

    const u64* wsn = ws_mask + (size_t)n * 2 * NWORDS;
    #pragma unroll
    for (int k = 0; k < 5; ++k)
        s_mask[w][k * 64 + lane] = wsn[k * 64 + lane];

    const float* posh   = pos   + (size_t)h * N_NODES * FEATS;
    const float* fieldh = field + (size_t)h * N_NODES * FEATS;
    const int q = lane & 3;
    const int g = lane >> 2;

    float4 A[2][2], F[2][2];
    #pragma unroll
    for (int sd = 0; sd < 2; ++sd) {
        const float4* pa = (const float4*)(posh   + (size_t)(sd ? dst : src) * FEATS);
        const float4* pf = (const float4*)(fieldh + (size_t)(sd ? src : dst) * FEATS);
        A[sd][0] = pa[q]; A[sd][1] = pa[q + 4];
        F[sd][0] = pf[q]; F[sd][1] = pf[q + 4];
    }

    const size_t sb = ((size_t)h * N_BATCH + n) * SAMPLES;
    int mm[8];
    #pragma unroll
    for (int c = 0; c < 8; ++c)
        mm[c] = (c < 4 ? mid0 : mid1)[sb + (c & 3) * 64 + lane];

    float num = 0.f, den = 0.f;
    #pragma unroll
    for (int c = 0; c < 8; ++c) {
        const int side = c >> 2;
        int    mArr[4];
        float4 B0[4], B1[4];
        #pragma unroll
        for (int t = 0; t < 4; ++t)
            mArr[t] = __shfl(mm[c], t * 16 + g);
        #pragma unroll
        for (int t = 0; t < 4; ++t) {
            const float4* rp = (const float4*)(posh + (size_t)mArr[t] * FEATS);
            B0[t] = rp[q];
            B1[t] = rp[q + 4];
        }
        #pragma unroll
        for (int t = 0; t < 4; ++t) {
            float dh = 0.f, nh = 0.f;
            {
                float4 a = A[side][0], f = F[side][0];
                float dx = a.x - B0[t].x, dy = a.y - B0[t].y,
                      dz = a.z - B0[t].z, dw = a.w - B0[t].w;
                dh += dx * f.x + dy * f.y + dz * f.z + dw * f.w;
                nh += dx * dx + dy * dy + dz * dz + dw * dw;
            }
            {
                float4 a = A[side][1], f = F[side][1];
                float dx = a.x - B1[t].x, dy = a.y - B1[t].y,
                      dz = a.z - B1[t].z, dw = a.w - B1[t].w;
                dh += dx * f.x + dy * f.y + dz * f.z + dw * f.w;
                nh += dx * dx + dy * dy + dz * dz + dw * dw;
            }
            dh += __shfl_xor(dh, 1); nh += __shfl_xor(nh, 1);
            dh += __shfl_xor(dh, 2); nh += __shfl_xor(nh, 2);
            const u64 wbits =
                s_mask[w][side * NWORDS + ((mArr[t] >> 8) << 2) + (mArr[t] & 3)];
            const float em = ((wbits >> ((mArr[t] >> 2) & 63)) & 1ull) ? U : -U;
            const float wgt = __expf(1.0f - sqrtf(nh));
            num += (dh + em) * wgt;
            den += wgt;
        }
    }
    #pragma unroll
    for (int off = 32; off > 0; off >>= 1) {
        num += __shfl_xor(num, off);
        den += __shfl_xor(den, off);
    }
    if (lane == 0)
        atomicAdd(out + n, 0.25f * (num / (den + 32.0f)));
}

extern "C" void kernel_launch(void* const* d_in, const int* in_sizes, int n_in,
                              void* d_out, int out_size, void* d_ws, size_t ws_size,
                              hipStream_t stream) {
    const int*   edge     = (const int*)  d_in[0];
    const int*   mid0     = (const int*)  d_in[1];
    const int*   mid1     = (const int*)  d_in[2];
    const float* pos      = (const float*)d_in[3];
    const float* field    = (const float*)d_in[4];
    const float* unc      = (const float*)d_in[5];
    const float* edge_mat = (const float*)d_in[6];
    float*       out      = (float*)d_out;

    if (ws_size >= (size_t)WS_NEEDED) {
        u64* mask_table = (u64*)d_ws;   // 12.8 MB, indexed by node id
        mask_dedup_kernel<<<2 * N_BATCH, 256, 0, stream>>>(edge, edge_mat,
                                                           mask_table, out);
        madgraph_kernel<<<N_BATCH, 256, 0, stream>>>(edge, mid0, mid1, pos,
                                                     field, unc, mask_table, out);
    } else {
        u64* ws_mask = (u64*)d_ws;      // 5.24 MB per-edge masks
        mask_kernel<<<N_BATCH, 256, 0, stream>>>(edge, edge_mat, ws_mask, out);
        madgraph_kernel_fb<<<N_BATCH, 256, 0, stream>>>(edge, mid0, mid1, pos,
                                                        field, unc, ws_mask, out);
    }
}